// Round 2
// baseline (81.549 us; speedup 1.0000x reference)
//
#include <hip/hip_runtime.h>
#include <stdint.h>

// AeTransformer_44839458570443: 3-NN inverse-distance interpolation + (tanh+1)/2.
// xyz1: [B,3,N] fp32, xyz2: [B,3,S] fp32, points2: [B,1,S] fp32 -> out [B,N] fp32.
//
// Strategy: bit-replicate the reference's float32 expanded-distance
//   d = (-2*((x*x'+y*y')+z*z') + ||q||^2) + ||p||^2      (all fp32, no FMA)
// and select top-3 by (d, index) (lax.top_k stable tie rule). Screening uses a
// packed key (quantized d | index) kept in a sorted 6-slot min-list via v_med3;
// survivors are re-scored with the identical fp32 sequence and sorted exactly.
static constexpr int B = 4;
static constexpr int N = 65536;
static constexpr int S = 512;

// Pack per-sample constants: (x, y, z, ((x*x + y*y) + z*z)) with IEEE fp32 ops
__global__ __launch_bounds__(256) void prep_kernel(const float* __restrict__ xyz2,
                                                   float4* __restrict__ ws) {
    int t = blockIdx.x * 256 + threadIdx.x;
    if (t >= B * S) return;
    int b = t / S, s = t - b * S;
    const float* p = xyz2 + (size_t)b * 3 * S;
    float x = p[s], y = p[s + S], z = p[s + 2 * S];
    float c = __fadd_rn(__fadd_rn(__fmul_rn(x, x), __fmul_rn(y, y)), __fmul_rn(z, z));
    ws[t] = make_float4(x, y, z, c);
}

// Reference-replicated fp32 distance (numpy order, no contraction)
__device__ __forceinline__ float ref_d(float x1, float y1, float z1, float ssrc, float4 p) {
    float dot = __fadd_rn(__fadd_rn(__fmul_rn(x1, p.x), __fmul_rn(y1, p.y)),
                          __fmul_rn(z1, p.z));
    float t = __fmul_rn(dot, -2.0f);
    return __fadd_rn(__fadd_rn(t, ssrc), p.w);
}

// compare-and-swap on (d, idx) ascending, idx ascending on exact float ties
#define CAS(da_, ia_, db_, ib_)                                     \
    {                                                               \
        bool sw_ = (db_ < da_) || ((db_ == da_) && (ib_ < ia_));    \
        float tda_ = sw_ ? db_ : da_;                               \
        int tia_ = sw_ ? ib_ : ia_;                                 \
        db_ = sw_ ? da_ : db_;                                      \
        ib_ = sw_ ? ia_ : ib_;                                      \
        da_ = tda_;                                                 \
        ia_ = tia_;                                                 \
    }

__global__ __launch_bounds__(256) void knn3_kernel(const float* __restrict__ xyz1,
                                                   const float* __restrict__ points2,
                                                   const float4* __restrict__ ws,
                                                   float* __restrict__ out) {
    int tid = blockIdx.x * 256 + threadIdx.x;   // B*N total
    int b = tid >> 16;                          // N = 65536
    int n = tid & (N - 1);
    const float* q = xyz1 + (size_t)b * 3 * N;
    float x1 = q[n], y1 = q[n + N], z1 = q[n + 2 * N];
    float ssrc = __fadd_rn(__fadd_rn(__fmul_rn(x1, x1), __fmul_rn(y1, y1)),
                           __fmul_rn(z1, z1));
    const float4* __restrict__ w = ws + b * S;

    // 6 smallest packed keys, ascending. Key = float(d + 0.25, low 9 mantissa
    // bits replaced by sample index). d >= -few-ulp so key > 0: float order ==
    // uint order; bias/truncation are monotone in d, so key order ==
    // (quantized d, index) lexicographic — a superset screen of the true
    // (d, index) top-3; survivors get exact treatment below.
    float m0 = 3.0e38f, m1 = 3.0e38f, m2 = 3.0e38f,
          m3 = 3.0e38f, m4 = 3.0e38f, m5 = 3.0e38f;
#pragma unroll 8
    for (int s = 0; s < S; ++s) {
        float4 p = w[s];  // wave-uniform index -> scalar loads
        float d = ref_d(x1, y1, z1, ssrc, p);
        float e = __fadd_rn(d, 0.25f);
        uint32_t kb = (__float_as_uint(e) & 0xFFFFFE00u) | (uint32_t)s;
        float k = __uint_as_float(kb);
        // branchless sorted insert: 1 min + 5 med3
        float t5 = __builtin_amdgcn_fmed3f(m4, k, m5);
        float t4 = __builtin_amdgcn_fmed3f(m3, k, m4);
        float t3 = __builtin_amdgcn_fmed3f(m2, k, m3);
        float t2 = __builtin_amdgcn_fmed3f(m1, k, m2);
        float t1 = __builtin_amdgcn_fmed3f(m0, k, m1);
        m0 = fminf(m0, k);
        m1 = t1; m2 = t2; m3 = t3; m4 = t4; m5 = t5;
    }

    // Re-score the 6 survivors with the identical replicated fp32 distance,
    // then sort exactly by (d, idx).
    int i0 = (int)(__float_as_uint(m0) & 511u);
    int i1 = (int)(__float_as_uint(m1) & 511u);
    int i2 = (int)(__float_as_uint(m2) & 511u);
    int i3 = (int)(__float_as_uint(m3) & 511u);
    int i4 = (int)(__float_as_uint(m4) & 511u);
    int i5 = (int)(__float_as_uint(m5) & 511u);
    float d0 = ref_d(x1, y1, z1, ssrc, w[i0]);
    float d1 = ref_d(x1, y1, z1, ssrc, w[i1]);
    float d2 = ref_d(x1, y1, z1, ssrc, w[i2]);
    float d3 = ref_d(x1, y1, z1, ssrc, w[i3]);
    float d4 = ref_d(x1, y1, z1, ssrc, w[i4]);
    float d5 = ref_d(x1, y1, z1, ssrc, w[i5]);

    // bubble smallest 3 to front (12 compare-exchanges)
    CAS(d4, i4, d5, i5); CAS(d3, i3, d4, i4); CAS(d2, i2, d3, i3); CAS(d1, i1, d2, i2); CAS(d0, i0, d1, i1);
    CAS(d4, i4, d5, i5); CAS(d3, i3, d4, i4); CAS(d2, i2, d3, i3); CAS(d1, i1, d2, i2);
    CAS(d4, i4, d5, i5); CAS(d3, i3, d4, i4); CAS(d2, i2, d3, i3);

    // Replicate reference weight/interp chain in fp32, nearest-first order:
    // recip = 1/(d+1e-8); weight = recip/sum; interp = sum(f*w); (tanh+1)/2
    const float EPS32 = 1e-8f;
    float r0 = __fdiv_rn(1.0f, __fadd_rn(d0, EPS32));
    float r1 = __fdiv_rn(1.0f, __fadd_rn(d1, EPS32));
    float r2 = __fdiv_rn(1.0f, __fadd_rn(d2, EPS32));
    float rs = __fadd_rn(__fadd_rn(r0, r1), r2);
    float w0 = __fdiv_rn(r0, rs);
    float w1 = __fdiv_rn(r1, rs);
    float w2 = __fdiv_rn(r2, rs);
    const float* f = points2 + (size_t)b * S;  // D = 1
    float interp = __fadd_rn(__fadd_rn(__fmul_rn(f[i0], w0), __fmul_rn(f[i1], w1)),
                             __fmul_rn(f[i2], w2));
    float t = tanhf(interp);
    out[tid] = __fmul_rn(__fadd_rn(t, 1.0f), 0.5f);
}

extern "C" void kernel_launch(void* const* d_in, const int* in_sizes, int n_in,
                              void* d_out, int out_size, void* d_ws, size_t ws_size,
                              hipStream_t stream) {
    const float* xyz1 = (const float*)d_in[0];
    const float* xyz2 = (const float*)d_in[1];
    const float* points2 = (const float*)d_in[2];
    float* out = (float*)d_out;
    float4* ws = (float4*)d_ws;  // B*S*16 = 32 KB

    prep_kernel<<<(B * S + 255) / 256, 256, 0, stream>>>(xyz2, ws);
    knn3_kernel<<<(B * N) / 256, 256, 0, stream>>>(xyz1, points2, ws, out);
}

// Round 3
// 48.989 us; speedup vs baseline: 1.6646x; 1.6646x over previous
//
#include <hip/hip_runtime.h>
#include <stdint.h>

// AeTransformer_44839458570443: 3-NN inverse-distance interpolation + (tanh+1)/2.
// xyz1: [B,3,N] fp32, xyz2: [B,3,S] fp32, points2: [B,1,S] fp32 -> out [B,N] fp32.
//
// Selection must bit-match the reference's float32 expanded distance
//   d = (-2*((x*x'+y*y')+z*z') + ||q||^2) + ||p||^2    (fp32, no FMA)
// ordered by (d, index). SCREEN: fast FMA proxy key (quantized d | index) in a
// sorted 6-slot min-list (v_med3). REFINE: survivors re-scored with the exact
// replicated fp32 sequence (proven in round 2) and sorted by (d, idx).
static constexpr int B = 4;
static constexpr int N = 65536;
static constexpr int S = 512;

// Pack per-sample constants: (x, y, z, ((x*x + y*y) + z*z)) with IEEE fp32 ops
__global__ __launch_bounds__(256) void prep_kernel(const float* __restrict__ xyz2,
                                                   float4* __restrict__ ws) {
    int t = blockIdx.x * 256 + threadIdx.x;
    if (t >= B * S) return;
    int b = t / S, s = t - b * S;
    const float* p = xyz2 + (size_t)b * 3 * S;
    float x = p[s], y = p[s + S], z = p[s + 2 * S];
    float c = __fadd_rn(__fadd_rn(__fmul_rn(x, x), __fmul_rn(y, y)), __fmul_rn(z, z));
    ws[t] = make_float4(x, y, z, c);
}

// Reference-replicated fp32 distance (numpy order, no contraction)
__device__ __forceinline__ float ref_d(float x1, float y1, float z1, float ssrc, float4 p) {
    float dot = __fadd_rn(__fadd_rn(__fmul_rn(x1, p.x), __fmul_rn(y1, p.y)),
                          __fmul_rn(z1, p.z));
    float t = __fmul_rn(dot, -2.0f);
    return __fadd_rn(__fadd_rn(t, ssrc), p.w);
}

// compare-and-swap on (d, idx) ascending, idx ascending on exact float ties
#define CAS(da_, ia_, db_, ib_)                                     \
    {                                                               \
        bool sw_ = (db_ < da_) || ((db_ == da_) && (ib_ < ia_));    \
        float tda_ = sw_ ? db_ : da_;                               \
        int tia_ = sw_ ? ib_ : ia_;                                 \
        db_ = sw_ ? da_ : db_;                                      \
        ib_ = sw_ ? ia_ : ib_;                                      \
        da_ = tda_;                                                 \
        ia_ = tia_;                                                 \
    }

__global__ __launch_bounds__(256) void knn3_kernel(const float* __restrict__ xyz1,
                                                   const float* __restrict__ points2,
                                                   const float4* __restrict__ ws,
                                                   float* __restrict__ out) {
    __shared__ float4 tile[S];  // 8 KB candidate table, read as uniform broadcast
    int b = blockIdx.x >> 8;                       // 256 blocks per batch (N/256)
    int n = ((blockIdx.x & 255) << 8) | threadIdx.x;

    // stage table: 2 float4 per thread
    const float4* __restrict__ wsrc = ws + b * S;
    tile[threadIdx.x] = wsrc[threadIdx.x];
    tile[threadIdx.x + 256] = wsrc[threadIdx.x + 256];
    __syncthreads();

    const float* q = xyz1 + (size_t)b * 3 * N;
    float x1 = q[n], y1 = q[n + N], z1 = q[n + 2 * N];
    float ssrc = __fadd_rn(__fadd_rn(__fmul_rn(x1, x1), __fmul_rn(y1, y1)),
                           __fmul_rn(z1, z1));
    // screen-only constants (rounding-free zone: screen is a monotone proxy)
    float c = ssrc + 0.25f;            // bias keeps key > 0 (d >= -1e-6)
    float nx2 = -2.0f * x1, ny2 = -2.0f * y1, nz2 = -2.0f * z1;
    uint32_t mask = 0xFFFFFE00u;       // in a VGPR: v_and_or_b32 allows 1 SGPR
    asm volatile("" : "+v"(mask));     // pin to VGPR

    // 6 smallest packed keys ascending; key = float(~(d+0.25), low 9 mantissa
    // bits = sample index). Monotone in (quantized d, idx); superset screen.
    float m0 = 3.0e38f, m1 = 3.0e38f, m2 = 3.0e38f,
          m3 = 3.0e38f, m4 = 3.0e38f, m5 = 3.0e38f;
#pragma unroll 8
    for (int s = 0; s < S; ++s) {
        float4 p = tile[s];  // uniform address -> ds_read_b128 broadcast
        float e = fmaf(nx2, p.x, fmaf(ny2, p.y, fmaf(nz2, p.z, p.w + c)));
        float k = __uint_as_float((__float_as_uint(e) & mask) | (uint32_t)s);
        // branchless sorted insert: 1 min + 5 med3
        float t5 = __builtin_amdgcn_fmed3f(m4, k, m5);
        float t4 = __builtin_amdgcn_fmed3f(m3, k, m4);
        float t3 = __builtin_amdgcn_fmed3f(m2, k, m3);
        float t2 = __builtin_amdgcn_fmed3f(m1, k, m2);
        float t1 = __builtin_amdgcn_fmed3f(m0, k, m1);
        m0 = fminf(m0, k);
        m1 = t1; m2 = t2; m3 = t3; m4 = t4; m5 = t5;
    }

    // Re-score the 6 survivors with the exact replicated fp32 distance,
    // then sort exactly by (d, idx).
    int i0 = (int)(__float_as_uint(m0) & 511u);
    int i1 = (int)(__float_as_uint(m1) & 511u);
    int i2 = (int)(__float_as_uint(m2) & 511u);
    int i3 = (int)(__float_as_uint(m3) & 511u);
    int i4 = (int)(__float_as_uint(m4) & 511u);
    int i5 = (int)(__float_as_uint(m5) & 511u);
    float d0 = ref_d(x1, y1, z1, ssrc, tile[i0]);
    float d1 = ref_d(x1, y1, z1, ssrc, tile[i1]);
    float d2 = ref_d(x1, y1, z1, ssrc, tile[i2]);
    float d3 = ref_d(x1, y1, z1, ssrc, tile[i3]);
    float d4 = ref_d(x1, y1, z1, ssrc, tile[i4]);
    float d5 = ref_d(x1, y1, z1, ssrc, tile[i5]);

    // bubble smallest 3 to front (12 compare-exchanges)
    CAS(d4, i4, d5, i5); CAS(d3, i3, d4, i4); CAS(d2, i2, d3, i3); CAS(d1, i1, d2, i2); CAS(d0, i0, d1, i1);
    CAS(d4, i4, d5, i5); CAS(d3, i3, d4, i4); CAS(d2, i2, d3, i3); CAS(d1, i1, d2, i2);
    CAS(d4, i4, d5, i5); CAS(d3, i3, d4, i4); CAS(d2, i2, d3, i3);

    // Replicate reference weight/interp chain in fp32, nearest-first order
    const float EPS32 = 1e-8f;
    float r0 = __fdiv_rn(1.0f, __fadd_rn(d0, EPS32));
    float r1 = __fdiv_rn(1.0f, __fadd_rn(d1, EPS32));
    float r2 = __fdiv_rn(1.0f, __fadd_rn(d2, EPS32));
    float rs = __fadd_rn(__fadd_rn(r0, r1), r2);
    float w0 = __fdiv_rn(r0, rs);
    float w1 = __fdiv_rn(r1, rs);
    float w2 = __fdiv_rn(r2, rs);
    const float* f = points2 + (size_t)b * S;  // D = 1
    float interp = __fadd_rn(__fadd_rn(__fmul_rn(f[i0], w0), __fmul_rn(f[i1], w1)),
                             __fmul_rn(f[i2], w2));
    float t = tanhf(interp);
    out[((size_t)b << 16) | n] = __fmul_rn(__fadd_rn(t, 1.0f), 0.5f);
}

extern "C" void kernel_launch(void* const* d_in, const int* in_sizes, int n_in,
                              void* d_out, int out_size, void* d_ws, size_t ws_size,
                              hipStream_t stream) {
    const float* xyz1 = (const float*)d_in[0];
    const float* xyz2 = (const float*)d_in[1];
    const float* points2 = (const float*)d_in[2];
    float* out = (float*)d_out;
    float4* ws = (float4*)d_ws;  // B*S*16 = 32 KB

    prep_kernel<<<(B * S + 255) / 256, 256, 0, stream>>>(xyz2, ws);
    knn3_kernel<<<(B * N) / 256, 256, 0, stream>>>(xyz1, points2, ws, out);
}